// Round 3
// baseline (103.609 us; speedup 1.0000x reference)
//
#include <hip/hip_runtime.h>
#include <hip/hip_bf16.h>
#include <math.h>
#include <stdint.h>

#define LOG_2PI_D 1.837877066409345483560659472811
#define LOG2E_D   1.442695040888963407359924681002
#define LN2_F     0.69314718055994530942f

typedef const float __attribute__((address_space(4))) cfloat;

// ---------------------------------------------------------------------------
// Single fused kernel. Per block: wave 0 recomputes the 6 quadratic-form
// coefficients per component (k = lane) and writes them to this block's
// private scratch slot; after threadfence+barrier all waves read them back
// through the constant address space -> s_load (scalar pipe, SGPR operands).
// Each thread then processes TWO points (float4 in, float2 out).
//   weighted[n,k]*log2e = C0*x0^2 + C1*x0*x1 + C2*x1^2 + C3*x0 + C4*x1 + C5
// ---------------------------------------------------------------------------
__global__ __launch_bounds__(256) void gmm_fused(
        const float* __restrict__ x,
        const float* __restrict__ means,
        const float* __restrict__ chol_var,
        const float* __restrict__ pi,
        float* __restrict__ out,
        float* __restrict__ scratch,
        int n2) {
    const int tid = threadIdx.x;
    const int bid = blockIdx.x;
    float* my = scratch + (size_t)bid * 384;

    if (tid < 64) {                       // exactly wave 0
        const int k = tid;
        // log_softmax(pi) across the wave
        float p = pi[k];
        float mx = p;
        #pragma unroll
        for (int off = 32; off > 0; off >>= 1) mx = fmaxf(mx, __shfl_xor(mx, off, 64));
        float sf = __expf(p - mx);
        #pragma unroll
        for (int off = 32; off > 0; off >>= 1) sf += __shfl_xor(sf, off, 64);
        double logpi = (double)p - (double)mx - (double)__logf(sf);

        // tril(chol_var) -> L ; cov = L L^T + eps I ; cholesky; precision
        double v00 = (double)chol_var[k*4 + 0];
        double v10 = (double)chol_var[k*4 + 2];
        double v11 = (double)chol_var[k*4 + 3];
        const double eps = 1e-6;
        double cov00 = v00*v00 + eps;
        double cov01 = v00*v10;
        double cov11 = v10*v10 + v11*v11 + eps;
        double a  = sqrt(cov00);
        double b  = cov01 / a;
        double c2 = cov11 - b*b;
        double logdet = (double)__logf((float)(cov00 * c2));
        double P00 = 1.0/cov00 + (b*b)/(cov00*c2);
        double P01 = -b/(a*c2);
        double P11 = 1.0/c2;
        double m0 = (double)means[k*2 + 0];
        double m1 = (double)means[k*2 + 1];
        double constk = -0.5*(2.0*LOG_2PI_D + logdet) + logpi;

        my[k*6 + 0] = (float)(-0.5*P00*LOG2E_D);
        my[k*6 + 1] = (float)(-P01*LOG2E_D);
        my[k*6 + 2] = (float)(-0.5*P11*LOG2E_D);
        my[k*6 + 3] = (float)((P00*m0 + P01*m1)*LOG2E_D);
        my[k*6 + 4] = (float)((P01*m0 + P11*m1)*LOG2E_D);
        my[k*6 + 5] = (float)((constk
                        - 0.5*(P00*m0*m0 + 2.0*P01*m0*m1 + P11*m1*m1))*LOG2E_D);
        __threadfence();                  // drain stores to L2 (device scope)
    }
    __syncthreads();

    // Launder the pointer so the AS4 loads below cannot be hoisted above the
    // stores/barrier (AMDGPU AA treats constant-AS as non-aliasing).
    const float* cp = my;
    asm volatile("" : "+s"(cp) :: "memory");
    cfloat* cc = (cfloat*)(uintptr_t)cp;

    int i = bid * 256 + tid;              // point-pair index
    if (i >= n2) return;

    float4 xv = reinterpret_cast<const float4*>(x)[i];
    float a00 = xv.x*xv.x, a01 = xv.x*xv.y, a11 = xv.y*xv.y;
    float b00 = xv.z*xv.z, b01 = xv.z*xv.w, b11 = xv.w*xv.w;

    float wa[64], wb[64];
    float ma = -INFINITY, mb = -INFINITY;
    #pragma unroll
    for (int k = 0; k < 64; ++k) {
        float C0 = cc[k*6+0], C1 = cc[k*6+1], C2 = cc[k*6+2];
        float C3 = cc[k*6+3], C4 = cc[k*6+4], C5 = cc[k*6+5];
        float ta = C5, tb = C5;
        ta = fmaf(C0, a00, ta);   tb = fmaf(C0, b00, tb);
        ta = fmaf(C1, a01, ta);   tb = fmaf(C1, b01, tb);
        ta = fmaf(C2, a11, ta);   tb = fmaf(C2, b11, tb);
        ta = fmaf(C3, xv.x, ta);  tb = fmaf(C3, xv.z, tb);
        ta = fmaf(C4, xv.y, ta);  tb = fmaf(C4, xv.w, tb);
        wa[k] = ta;  wb[k] = tb;
        ma = fmaxf(ma, ta);  mb = fmaxf(mb, tb);
    }

    float sa0 = 0.f, sa1 = 0.f, sb0 = 0.f, sb1 = 0.f;
    #pragma unroll
    for (int k = 0; k < 64; k += 2) {
        sa0 += __builtin_amdgcn_exp2f(wa[k]   - ma);
        sa1 += __builtin_amdgcn_exp2f(wa[k+1] - ma);
        sb0 += __builtin_amdgcn_exp2f(wb[k]   - mb);
        sb1 += __builtin_amdgcn_exp2f(wb[k+1] - mb);
    }
    float2 o;
    o.x = LN2_F * (ma + __builtin_amdgcn_logf(sa0 + sa1));
    o.y = LN2_F * (mb + __builtin_amdgcn_logf(sb0 + sb1));
    reinterpret_cast<float2*>(out)[i] = o;
}

extern "C" void kernel_launch(void* const* d_in, const int* in_sizes, int n_in,
                              void* d_out, int out_size, void* d_ws, size_t ws_size,
                              hipStream_t stream) {
    const float* x        = (const float*)d_in[0];
    const float* means    = (const float*)d_in[1];
    const float* chol_var = (const float*)d_in[2];
    const float* pi       = (const float*)d_in[3];
    float* out     = (float*)d_out;
    float* scratch = (float*)d_ws;        // 1024 blocks * 384 floats = 1.5 MB

    int n  = in_sizes[0] / 2;             // 524288 points
    int n2 = n / 2;                       // 262144 point-pairs
    int blocks = (n2 + 255) / 256;        // 1024

    gmm_fused<<<blocks, 256, 0, stream>>>(x, means, chol_var, pi, out, scratch, n2);
}

// Round 4
// 73.208 us; speedup vs baseline: 1.4153x; 1.4153x over previous
//
#include <hip/hip_runtime.h>
#include <hip/hip_bf16.h>
#include <math.h>
#include <stdint.h>

#define LOG_2PI_D 1.837877066409345483560659472811
#define LOG2E_D   1.442695040888963407359924681002
#define LN2_F     0.69314718055994530942f

typedef const float __attribute__((address_space(4))) cfloat;

// ---------------------------------------------------------------------------
// Single fused kernel. Every block's wave 0 redundantly computes the 6
// quadratic-form coefficients per component (k = lane) and stores them to ONE
// shared 1.5 KB slot in d_ws (all blocks write bit-identical values -> benign
// race). Visibility needed is only CU-local: vector stores drain to L2 with
// s_waitcnt vmcnt(0); s_load K$ misses refill from L2. NO __threadfence --
// device-scope fence emits buffer_wbl2 (full L2 writeback) per block, which
// was the round-3 disaster (48us, VALUBusy 15%).
// After __syncthreads, all waves read the table through constant address
// space -> s_load on the scalar pipe (SGPR operands, K$-hot).
// Each thread processes TWO points (float4 in, float2 out).
//   weighted[n,k]*log2e = C0*x0^2 + C1*x0*x1 + C2*x1^2 + C3*x0 + C4*x1 + C5
// __launch_bounds__(256,2): allow ~256 VGPRs so wa[64]/wb[64] stay in
// registers (round 3's VGPR=72 showed remat/spill under the default budget).
// ---------------------------------------------------------------------------
__global__ __launch_bounds__(256, 2) void gmm_fused(
        const float* __restrict__ x,
        const float* __restrict__ means,
        const float* __restrict__ chol_var,
        const float* __restrict__ pi,
        float* __restrict__ out,
        float* scratch,
        int n2) {
    const int tid = threadIdx.x;
    const int bid = blockIdx.x;

    if (tid < 64) {                       // exactly wave 0
        const int k = tid;
        // log_softmax(pi) across the wave
        float p = pi[k];
        float mx = p;
        #pragma unroll
        for (int off = 32; off > 0; off >>= 1) mx = fmaxf(mx, __shfl_xor(mx, off, 64));
        float sf = __expf(p - mx);
        #pragma unroll
        for (int off = 32; off > 0; off >>= 1) sf += __shfl_xor(sf, off, 64);
        double logpi = (double)p - (double)mx - (double)__logf(sf);

        // tril(chol_var) -> L ; cov = L L^T + eps I ; cholesky; precision
        double v00 = (double)chol_var[k*4 + 0];
        double v10 = (double)chol_var[k*4 + 2];
        double v11 = (double)chol_var[k*4 + 3];
        const double eps = 1e-6;
        double cov00 = v00*v00 + eps;
        double cov01 = v00*v10;
        double cov11 = v10*v10 + v11*v11 + eps;
        double a  = sqrt(cov00);
        double b  = cov01 / a;
        double c2 = cov11 - b*b;
        double logdet = (double)__logf((float)(cov00 * c2));
        double P00 = 1.0/cov00 + (b*b)/(cov00*c2);
        double P01 = -b/(a*c2);
        double P11 = 1.0/c2;
        double m0 = (double)means[k*2 + 0];
        double m1 = (double)means[k*2 + 1];
        double constk = -0.5*(2.0*LOG_2PI_D + logdet) + logpi;

        scratch[k*6 + 0] = (float)(-0.5*P00*LOG2E_D);
        scratch[k*6 + 1] = (float)(-P01*LOG2E_D);
        scratch[k*6 + 2] = (float)(-0.5*P11*LOG2E_D);
        scratch[k*6 + 3] = (float)((P00*m0 + P01*m1)*LOG2E_D);
        scratch[k*6 + 4] = (float)((P01*m0 + P11*m1)*LOG2E_D);
        scratch[k*6 + 5] = (float)((constk
                        - 0.5*(P00*m0*m0 + 2.0*P01*m0*m1 + P11*m1*m1))*LOG2E_D);
        // CU-local visibility only: drain stores to L2. No buffer_wbl2!
        asm volatile("s_waitcnt vmcnt(0)" ::: "memory");
    }
    __syncthreads();

    // Launder the pointer so the AS4 loads below cannot be hoisted above the
    // stores/barrier (AMDGPU AA treats constant-AS as non-aliasing).
    const float* cp = scratch;
    asm volatile("" : "+s"(cp) :: "memory");
    cfloat* cc = (cfloat*)(uintptr_t)cp;

    int i = bid * 256 + tid;              // point-pair index
    if (i >= n2) return;

    float4 xv = reinterpret_cast<const float4*>(x)[i];
    float a00 = xv.x*xv.x, a01 = xv.x*xv.y, a11 = xv.y*xv.y;
    float b00 = xv.z*xv.z, b01 = xv.z*xv.w, b11 = xv.w*xv.w;

    float wa[64], wb[64];
    float ma = -INFINITY, mb = -INFINITY;
    #pragma unroll
    for (int k = 0; k < 64; ++k) {
        float C0 = cc[k*6+0], C1 = cc[k*6+1], C2 = cc[k*6+2];
        float C3 = cc[k*6+3], C4 = cc[k*6+4], C5 = cc[k*6+5];
        float ta = C5, tb = C5;
        ta = fmaf(C0, a00, ta);   tb = fmaf(C0, b00, tb);
        ta = fmaf(C1, a01, ta);   tb = fmaf(C1, b01, tb);
        ta = fmaf(C2, a11, ta);   tb = fmaf(C2, b11, tb);
        ta = fmaf(C3, xv.x, ta);  tb = fmaf(C3, xv.z, tb);
        ta = fmaf(C4, xv.y, ta);  tb = fmaf(C4, xv.w, tb);
        wa[k] = ta;  wb[k] = tb;
        ma = fmaxf(ma, ta);  mb = fmaxf(mb, tb);
    }

    float sa0 = 0.f, sa1 = 0.f, sb0 = 0.f, sb1 = 0.f;
    #pragma unroll
    for (int k = 0; k < 64; k += 2) {
        sa0 += __builtin_amdgcn_exp2f(wa[k]   - ma);
        sa1 += __builtin_amdgcn_exp2f(wa[k+1] - ma);
        sb0 += __builtin_amdgcn_exp2f(wb[k]   - mb);
        sb1 += __builtin_amdgcn_exp2f(wb[k+1] - mb);
    }
    float2 o;
    o.x = LN2_F * (ma + __builtin_amdgcn_logf(sa0 + sa1));
    o.y = LN2_F * (mb + __builtin_amdgcn_logf(sb0 + sb1));
    reinterpret_cast<float2*>(out)[i] = o;
}

extern "C" void kernel_launch(void* const* d_in, const int* in_sizes, int n_in,
                              void* d_out, int out_size, void* d_ws, size_t ws_size,
                              hipStream_t stream) {
    const float* x        = (const float*)d_in[0];
    const float* means    = (const float*)d_in[1];
    const float* chol_var = (const float*)d_in[2];
    const float* pi       = (const float*)d_in[3];
    float* out     = (float*)d_out;
    float* scratch = (float*)d_ws;        // one shared 384-float slot

    int n  = in_sizes[0] / 2;             // 524288 points
    int n2 = n / 2;                       // 262144 point-pairs
    int blocks = (n2 + 255) / 256;        // 1024

    gmm_fused<<<blocks, 256, 0, stream>>>(x, means, chol_var, pi, out, scratch, n2);
}

// Round 5
// 71.402 us; speedup vs baseline: 1.4511x; 1.0253x over previous
//
#include <hip/hip_runtime.h>
#include <hip/hip_bf16.h>
#include <math.h>
#include <stdint.h>

#define LOG_2PI_D 1.837877066409345483560659472811
#define LOG2E_D   1.442695040888963407359924681002
#define LN2_F     0.69314718055994530942f

typedef float v2f __attribute__((ext_vector_type(2)));

// broadcast lane `l` of v to all lanes (SGPR result); l must be compile-time
__device__ __forceinline__ float rl(float v, int l) {
    return __builtin_bit_cast(float,
        __builtin_amdgcn_readlane(__builtin_bit_cast(int, v), l));
}

// ---------------------------------------------------------------------------
// Single fused kernel, no scratch memory. EVERY wave redundantly computes the
// per-component quadratic-form coefficients (lane = component k): ~400 cycles
// of fp64 algebra + two 6-step shuffle reductions, no barrier, no stores, no
// cross-block races (round-4 lesson: the global-scratch round trip + same-line
// write contention cost more than a second launch).
// The k-loop broadcasts coefficients with v_readlane (k is a literal from the
// unrolled loop -> SGPR operand on the FMA, one SGPR per instr: legal).
// Two points are packed per thread into v2f so pass-1 runs on v_pk_fma_f32 /
// v_pk_max_f32 (VOP3P packed fp32).
//   weighted[n,k]*log2e = C0*x0^2 + C1*x0*x1 + C2*x1^2 + C3*x0 + C4*x1 + C5
// ---------------------------------------------------------------------------
__global__ __launch_bounds__(256, 2) void gmm_fused(
        const float* __restrict__ x,
        const float* __restrict__ means,
        const float* __restrict__ chol_var,
        const float* __restrict__ pi,
        float* __restrict__ out,
        int n2) {
    const int lane = threadIdx.x & 63;

    // ---- per-wave setup: lane k owns component k ----
    {
    }
    const int k = lane;
    float p = pi[k];
    float mx = p;
    #pragma unroll
    for (int off = 32; off > 0; off >>= 1) mx = fmaxf(mx, __shfl_xor(mx, off, 64));
    float sf = __expf(p - mx);
    #pragma unroll
    for (int off = 32; off > 0; off >>= 1) sf += __shfl_xor(sf, off, 64);
    double logpi = (double)p - (double)mx - (double)__logf(sf);

    double v00 = (double)chol_var[k*4 + 0];
    double v10 = (double)chol_var[k*4 + 2];
    double v11 = (double)chol_var[k*4 + 3];
    const double eps = 1e-6;
    double cov00 = v00*v00 + eps;
    double cov01 = v00*v10;
    double cov11 = v10*v10 + v11*v11 + eps;
    double a  = sqrt(cov00);
    double b  = cov01 / a;
    double c2 = cov11 - b*b;
    double logdet = (double)__logf((float)(cov00 * c2));
    double P00 = 1.0/cov00 + (b*b)/(cov00*c2);
    double P01 = -b/(a*c2);
    double P11 = 1.0/c2;
    double m0 = (double)means[k*2 + 0];
    double m1 = (double)means[k*2 + 1];
    double constk = -0.5*(2.0*LOG_2PI_D + logdet) + logpi;

    float C0 = (float)(-0.5*P00*LOG2E_D);
    float C1 = (float)(-P01*LOG2E_D);
    float C2 = (float)(-0.5*P11*LOG2E_D);
    float C3 = (float)((P00*m0 + P01*m1)*LOG2E_D);
    float C4 = (float)((P01*m0 + P11*m1)*LOG2E_D);
    float C5 = (float)((constk
                 - 0.5*(P00*m0*m0 + 2.0*P01*m0*m1 + P11*m1*m1))*LOG2E_D);

    // ---- main: two points per thread, packed ----
    int i = blockIdx.x * 256 + threadIdx.x;   // point-pair index
    if (i >= n2) return;

    float4 xv = reinterpret_cast<const float4*>(x)[i];
    v2f X0  = { xv.x, xv.z };
    v2f X1  = { xv.y, xv.w };
    v2f Q00 = X0 * X0;
    v2f Q01 = X0 * X1;
    v2f Q11 = X1 * X1;

    v2f w2[64];
    v2f m2 = { -INFINITY, -INFINITY };
    #pragma unroll
    for (int kk = 0; kk < 64; ++kk) {
        float c0 = rl(C0, kk), c1 = rl(C1, kk), c2f = rl(C2, kk);
        float c3 = rl(C3, kk), c4 = rl(C4, kk), c5 = rl(C5, kk);
        v2f t = { c5, c5 };
        t = __builtin_elementwise_fma((v2f){c0, c0}, Q00, t);
        t = __builtin_elementwise_fma((v2f){c1, c1}, Q01, t);
        t = __builtin_elementwise_fma((v2f){c2f, c2f}, Q11, t);
        t = __builtin_elementwise_fma((v2f){c3, c3}, X0,  t);
        t = __builtin_elementwise_fma((v2f){c4, c4}, X1,  t);
        w2[kk] = t;
        m2 = __builtin_elementwise_max(m2, t);
    }

    float sa0 = 0.f, sa1 = 0.f, sb0 = 0.f, sb1 = 0.f;
    #pragma unroll
    for (int kk = 0; kk < 64; kk += 2) {
        v2f d0 = w2[kk]     - m2;
        v2f d1 = w2[kk + 1] - m2;
        sa0 += __builtin_amdgcn_exp2f(d0.x);
        sb0 += __builtin_amdgcn_exp2f(d0.y);
        sa1 += __builtin_amdgcn_exp2f(d1.x);
        sb1 += __builtin_amdgcn_exp2f(d1.y);
    }
    float2 o;
    o.x = LN2_F * (m2.x + __builtin_amdgcn_logf(sa0 + sa1));
    o.y = LN2_F * (m2.y + __builtin_amdgcn_logf(sb0 + sb1));
    reinterpret_cast<float2*>(out)[i] = o;
}

extern "C" void kernel_launch(void* const* d_in, const int* in_sizes, int n_in,
                              void* d_out, int out_size, void* d_ws, size_t ws_size,
                              hipStream_t stream) {
    const float* x        = (const float*)d_in[0];
    const float* means    = (const float*)d_in[1];
    const float* chol_var = (const float*)d_in[2];
    const float* pi       = (const float*)d_in[3];
    float* out = (float*)d_out;

    int n  = in_sizes[0] / 2;             // 524288 points
    int n2 = n / 2;                       // 262144 point-pairs
    int blocks = (n2 + 255) / 256;        // 1024

    gmm_fused<<<blocks, 256, 0, stream>>>(x, means, chol_var, pi, out, n2);
}

// Round 6
// 70.203 us; speedup vs baseline: 1.4758x; 1.0171x over previous
//
#include <hip/hip_runtime.h>
#include <hip/hip_bf16.h>
#include <math.h>
#include <stdint.h>

#define LOG_2PI_D 1.837877066409345483560659472811
#define LOG2E_D   1.442695040888963407359924681002
#define LN2_F     0.69314718055994530942f

typedef float v2f __attribute__((ext_vector_type(2)));
typedef const float __attribute__((address_space(4))) cfloat;

// ---------------------------------------------------------------------------
// Setup: one wave, lane = component k. Emits 6 coefficients per k (scaled by
// log2 e) such that  weighted[n,k]*log2e = C0 x0^2 + C1 x0x1 + C2 x1^2
//                                        + C3 x0 + C4 x1 + C5.
// (Two-kernel structure measured fastest: R2 69.5 vs fused variants 71-104.
//  Scratch-broadcast (R4) and readlane-broadcast (R5) both cost more than the
//  second launch.)
// ---------------------------------------------------------------------------
__global__ void gmm_setup(const float* __restrict__ means,
                          const float* __restrict__ chol_var,
                          const float* __restrict__ pi,
                          float* __restrict__ coef) {
    int k = threadIdx.x;  // 0..63

    float p = pi[k];
    float mx = p;
    #pragma unroll
    for (int off = 32; off > 0; off >>= 1) mx = fmaxf(mx, __shfl_xor(mx, off, 64));
    float sf = __expf(p - mx);
    #pragma unroll
    for (int off = 32; off > 0; off >>= 1) sf += __shfl_xor(sf, off, 64);
    double logpi = (double)p - (double)mx - (double)__logf(sf);

    double v00 = (double)chol_var[k*4 + 0];
    double v10 = (double)chol_var[k*4 + 2];
    double v11 = (double)chol_var[k*4 + 3];
    const double eps = 1e-6;
    double cov00 = v00*v00 + eps;
    double cov01 = v00*v10;
    double cov11 = v10*v10 + v11*v11 + eps;
    double a  = sqrt(cov00);
    double b  = cov01 / a;
    double c2 = cov11 - b*b;
    double logdet = (double)__logf((float)(cov00 * c2));
    double P00 = 1.0/cov00 + (b*b)/(cov00*c2);
    double P01 = -b/(a*c2);
    double P11 = 1.0/c2;
    double m0 = (double)means[k*2 + 0];
    double m1 = (double)means[k*2 + 1];
    double constk = -0.5*(2.0*LOG_2PI_D + logdet) + logpi;

    coef[k*6 + 0] = (float)(-0.5*P00*LOG2E_D);
    coef[k*6 + 1] = (float)(-P01*LOG2E_D);
    coef[k*6 + 2] = (float)(-0.5*P11*LOG2E_D);
    coef[k*6 + 3] = (float)((P00*m0 + P01*m1)*LOG2E_D);
    coef[k*6 + 4] = (float)((P01*m0 + P11*m1)*LOG2E_D);
    coef[k*6 + 5] = (float)((constk
                     - 0.5*(P00*m0*m0 + 2.0*P01*m0*m1 + P11*m1*m1))*LOG2E_D);
}

// ---------------------------------------------------------------------------
// Main: TWO points per thread, packed into v2f so pass-1 is 6 VOP3P packed
// ops per component per pair (v_pk_fma_f32 with SGPR-broadcast coefficient).
// Coefficients come in through the constant address space -> s_load on the
// scalar pipe (zero VALU cost; R5's v_readlane broadcast costs 384 VALU ops).
// __launch_bounds__(256,2): w2[64] v2f = 128 VGPRs must stay in registers.
// ---------------------------------------------------------------------------
__global__ __launch_bounds__(256, 2) void gmm_main(const float* __restrict__ x,
                                                   const float* __restrict__ coef,
                                                   float* __restrict__ out,
                                                   int n2) {
    int i = blockIdx.x * 256 + threadIdx.x;   // point-pair index
    if (i >= n2) return;

    cfloat* cc = (cfloat*)(uintptr_t)coef;

    float4 xv = reinterpret_cast<const float4*>(x)[i];
    v2f X0  = { xv.x, xv.z };
    v2f X1  = { xv.y, xv.w };
    v2f Q00 = X0 * X0;
    v2f Q01 = X0 * X1;
    v2f Q11 = X1 * X1;

    v2f w2[64];
    v2f m2 = { -INFINITY, -INFINITY };
    #pragma unroll
    for (int k = 0; k < 64; ++k) {
        float c0 = cc[k*6+0], c1 = cc[k*6+1], c2 = cc[k*6+2];
        float c3 = cc[k*6+3], c4 = cc[k*6+4], c5 = cc[k*6+5];
        v2f t = __builtin_elementwise_fma((v2f){c0, c0}, Q00, (v2f){c5, c5});
        t = __builtin_elementwise_fma((v2f){c1, c1}, Q01, t);
        t = __builtin_elementwise_fma((v2f){c2, c2}, Q11, t);
        t = __builtin_elementwise_fma((v2f){c3, c3}, X0,  t);
        t = __builtin_elementwise_fma((v2f){c4, c4}, X1,  t);
        w2[k] = t;
        m2 = __builtin_elementwise_max(m2, t);
    }

    float sa0 = 0.f, sa1 = 0.f, sb0 = 0.f, sb1 = 0.f;
    #pragma unroll
    for (int k = 0; k < 64; k += 2) {
        v2f d0 = w2[k]     - m2;
        v2f d1 = w2[k + 1] - m2;
        sa0 += __builtin_amdgcn_exp2f(d0.x);
        sb0 += __builtin_amdgcn_exp2f(d0.y);
        sa1 += __builtin_amdgcn_exp2f(d1.x);
        sb1 += __builtin_amdgcn_exp2f(d1.y);
    }
    float2 o;
    o.x = LN2_F * (m2.x + __builtin_amdgcn_logf(sa0 + sa1));
    o.y = LN2_F * (m2.y + __builtin_amdgcn_logf(sb0 + sb1));
    reinterpret_cast<float2*>(out)[i] = o;
}

extern "C" void kernel_launch(void* const* d_in, const int* in_sizes, int n_in,
                              void* d_out, int out_size, void* d_ws, size_t ws_size,
                              hipStream_t stream) {
    const float* x        = (const float*)d_in[0];
    const float* means    = (const float*)d_in[1];
    const float* chol_var = (const float*)d_in[2];
    const float* pi       = (const float*)d_in[3];
    float* out  = (float*)d_out;
    float* coef = (float*)d_ws;           // 384 floats

    int n  = in_sizes[0] / 2;             // 524288 points
    int n2 = n / 2;                       // 262144 point-pairs
    int blocks = (n2 + 255) / 256;        // 1024

    gmm_setup<<<1, 64, 0, stream>>>(means, chol_var, pi, coef);
    gmm_main<<<blocks, 256, 0, stream>>>(x, coef, out, n2);
}